// Round 17
// baseline (620.806 us; speedup 1.0000x reference)
//
#include <hip/hip_runtime.h>
#include <math.h>
#include <stdint.h>

typedef __bf16 bf16_t;
typedef __bf16 bf16x8 __attribute__((ext_vector_type(8)));
typedef float f32x4 __attribute__((ext_vector_type(4)));
typedef unsigned short ushort8_t __attribute__((ext_vector_type(8)));
typedef unsigned short ushort4_t __attribute__((ext_vector_type(4)));

#define LOG2E 1.44269504088896340736f
#define PRIO(p) __builtin_amdgcn_s_setprio(p)

__device__ inline unsigned short f2bf_bits(float f) {
  union { float f; unsigned int u; } v; v.f = f;
  unsigned int u = v.u;
  return (unsigned short)((u + 0x7fffu + ((u >> 16) & 1u)) >> 16);
}

// global -> LDS direct copy, 16B per lane. LDS dest is wave-uniform base
// + lane*16 (HW behavior, m104); global src is per-lane.
__device__ inline void gld_lds16(const void* g, void* l) {
  __builtin_amdgcn_global_load_lds(
      (__attribute__((address_space(1))) void*)(uintptr_t)(g),
      (__attribute__((address_space(3))) void*)(uintptr_t)(l),
      16, 0, 0);
}

// ---------------- cast fp32 -> bf16 (weights) ----------------
__global__ __launch_bounds__(256) void cast_kernel(const float* __restrict__ in,
                                                   unsigned short* __restrict__ out,
                                                   int n) {
  int i = (blockIdx.x * 256 + threadIdx.x) * 4;
  if (i >= n) return;
  float4 f = *reinterpret_cast<const float4*>(in + i);
  ushort4_t o;
  o[0] = f2bf_bits(f.x); o[1] = f2bf_bits(f.y);
  o[2] = f2bf_bits(f.z); o[3] = f2bf_bits(f.w);
  *reinterpret_cast<ushort4_t*>(out + i) = o;
}

// ---------------- LayerNorm (C=1024) + cast to bf16 ----------------
__global__ __launch_bounds__(256) void ln_kernel(const float* __restrict__ x,
                                                 const float* __restrict__ g,
                                                 const float* __restrict__ bta,
                                                 unsigned short* __restrict__ out) {
  const int row = blockIdx.x;
  const int c = threadIdx.x * 4;
  const float4 xv = *reinterpret_cast<const float4*>(x + (size_t)row * 1024 + c);
  float s = xv.x + xv.y + xv.z + xv.w;
  float sq = xv.x * xv.x + xv.y * xv.y + xv.z * xv.z + xv.w * xv.w;
#pragma unroll
  for (int xm = 1; xm < 64; xm <<= 1) {
    s += __shfl_xor(s, xm, 64);
    sq += __shfl_xor(sq, xm, 64);
  }
  __shared__ float sh[8];
  const int wave = threadIdx.x >> 6, lane = threadIdx.x & 63;
  if (lane == 0) { sh[wave] = s; sh[4 + wave] = sq; }
  __syncthreads();
  const float ts = sh[0] + sh[1] + sh[2] + sh[3];
  const float tq = sh[4] + sh[5] + sh[6] + sh[7];
  const float mean = ts * (1.0f / 1024.0f);
  const float var = tq * (1.0f / 1024.0f) - mean * mean;
  const float rstd = rsqrtf(var + 1e-5f);
  const float4 gv = *reinterpret_cast<const float4*>(g + c);
  const float4 bv = *reinterpret_cast<const float4*>(bta + c);
  ushort4_t o;
  o[0] = f2bf_bits((xv.x - mean) * rstd * gv.x + bv.x);
  o[1] = f2bf_bits((xv.y - mean) * rstd * gv.y + bv.y);
  o[2] = f2bf_bits((xv.z - mean) * rstd * gv.z + bv.z);
  o[3] = f2bf_bits((xv.w - mean) * rstd * gv.w + bv.w);
  *reinterpret_cast<ushort4_t*>(out + (size_t)row * 1024 + c) = o;
}

// ---------------- GEMM m97-build-replica (R16, FROZEN) ----------------------
// Best measured GEMM config (R16: fc1 102us / 674 TF, MfmaUtil 31%, 0
// conflicts): 128^2 tile, 4 waves, BK=64, single 32KiB LDS, plain
// __syncthreads, NO launch_bounds (allocator freedom), compile-time N/K.
template <int EPI, int NN, int KK>  // EPI: 0 bias->bf16; 1 bias+res->f32; 2 bias+GELU->bf16
__global__ void gemmS(const unsigned short* __restrict__ A,
                      const unsigned short* __restrict__ W,
                      const float* __restrict__ bias,
                      const float* __restrict__ res,
                      unsigned short* __restrict__ outb,
                      float* __restrict__ outf) {
  __shared__ unsigned short lds[2 * 128 * 64];  // 32 KiB: A then B
  const int tid = threadIdx.x;
  const int wave = tid >> 6, l = tid & 63;
  const int m0 = blockIdx.y * 128, n0 = blockIdx.x * 128;
  const int wm = wave >> 1, wn = wave & 1;   // 2x2 wave grid
  const int lr16 = l & 15, lk = l >> 4;
  const int axor = (lr16 & 7) << 3;          // read-side XOR (row&7 == lr16&7)
  const int B0 = 128 * 64;

  const int sr = tid >> 3;
  const int sx = ((tid & 7) ^ (sr & 7)) << 3;

  f32x4 acc[4][4];
#pragma unroll
  for (int i = 0; i < 4; ++i)
#pragma unroll
    for (int j = 0; j < 4; ++j) { f32x4 z = {0.f, 0.f, 0.f, 0.f}; acc[i][j] = z; }

  const int nt = KK / 64;
  for (int t = 0; t < nt; ++t) {
#pragma unroll
    for (int h = 0; h < 4; ++h)
      gld_lds16(A + (size_t)(m0 + h * 32 + sr) * KK + t * 64 + sx,
                &lds[h * 2048 + tid * 8]);
#pragma unroll
    for (int h = 0; h < 4; ++h)
      gld_lds16(W + (size_t)(n0 + h * 32 + sr) * KK + t * 64 + sx,
                &lds[B0 + h * 2048 + tid * 8]);
    __syncthreads();  // compiler emits the vmcnt/lgkm drain here

    bf16x8 af0[4], af1[4];
#pragma unroll
    for (int mi = 0; mi < 4; ++mi) {
      const int arow = (wm * 64 + mi * 16 + lr16) * 64;
      af0[mi] = *reinterpret_cast<const bf16x8*>(&lds[arow + ((lk * 8) ^ axor)]);
      af1[mi] = *reinterpret_cast<const bf16x8*>(&lds[arow + ((32 + lk * 8) ^ axor)]);
    }
#pragma unroll
    for (int ni = 0; ni < 4; ++ni) {
      const int brow = (wn * 64 + ni * 16 + lr16) * 64;
      const bf16x8 b0 = *reinterpret_cast<const bf16x8*>(
          &lds[B0 + brow + ((lk * 8) ^ axor)]);
      const bf16x8 b1 = *reinterpret_cast<const bf16x8*>(
          &lds[B0 + brow + ((32 + lk * 8) ^ axor)]);
#pragma unroll
      for (int mi = 0; mi < 4; ++mi) {
        acc[mi][ni] =
            __builtin_amdgcn_mfma_f32_16x16x32_bf16(af0[mi], b0, acc[mi][ni], 0, 0, 0);
        acc[mi][ni] =
            __builtin_amdgcn_mfma_f32_16x16x32_bf16(af1[mi], b1, acc[mi][ni], 0, 0, 0);
      }
    }
    __syncthreads();  // all reads done before next tile's gld_lds overwrites
  }

  // epilogue: C row=(l>>4)*4+r, col=l&15 per 16x16 fragment (m89/m91)
#pragma unroll
  for (int ni = 0; ni < 4; ++ni) {
    const int col = n0 + wn * 64 + ni * 16 + lr16;
    const float bv = bias[col];
#pragma unroll
    for (int mi = 0; mi < 4; ++mi) {
#pragma unroll
      for (int r = 0; r < 4; ++r) {
        const int row = m0 + wm * 64 + mi * 16 + lk * 4 + r;
        const size_t idx = (size_t)row * NN + col;
        float v = acc[mi][ni][r] + bv;
        if (EPI == 0) {
          outb[idx] = f2bf_bits(v);
        } else if (EPI == 1) {
          outf[idx] = v + res[idx];
        } else {
          v = 0.5f * v * (1.0f + erff(v * 0.70710678118654752f));
          outb[idx] = f2bf_bits(v);
        }
      }
    }
  }
}

// ---------------- causal flash attention v3 (R17) ---------------------------
// R17 changes vs R16 (attn was 102us, MfmaUtil 7.3%, VALUBusy 56% -> VALU-
// bound; catalog levers for exactly this regime):
//  (a) T5 setprio(1) around QK^T and PV MFMA clusters (+4-7% attn, m191 —
//      independent blocks per CU at different phases = our regime).
//  (b) T13 defer-max THR=8: skip O-rescale + m-update when
//      __all(mx - m <= 8); P bounded by e^8~2980 (bf16/f32 safe; m214
//      verified refcheck'd + data-independent).
//  (c) NO __launch_bounds__ (R16 lesson: allocator freedom won on GEMM).
// Structure otherwise identical (paired q-tiles, dbuf K/V, XOR swizzle).
__device__ inline int swz(int row, int colelem) {
  return row * 64 + (colelem ^ ((row & 7) << 3));
}

__global__ void attn_kernel(const unsigned short* __restrict__ kqv,
                            unsigned short* __restrict__ y) {
  __shared__ unsigned short Ks[2][64 * 64];
  __shared__ unsigned short Vt[2][64 * 64];
  __shared__ unsigned short Ps[4][16 * 64];

  const int tid = threadIdx.x;
  const int wave = tid >> 6;
  const int lane = tid & 63;
  const int bh = blockIdx.x;
  const int pair = blockIdx.y;
  const int b = bh >> 4;
  const int h = bh & 15;
  const int lo = pair;
  const int hi = 15 - pair;
  const int bT = b * 1024;
  const int hoff = h * 192;

  auto loadq = [&](int q0t, bf16x8 (&qf)[2]) {
    const unsigned short* qp =
        kqv + (size_t)(bT + q0t + wave * 16 + (lane & 15)) * 3072 + hoff + 64 +
        (lane >> 4) * 8;
#pragma unroll
    for (int kk = 0; kk < 2; ++kk) {
      bf16x8 t = *reinterpret_cast<const bf16x8*>(qp + kk * 32);
#pragma unroll
      for (int e = 0; e < 8; ++e) t[e] = (bf16_t)((float)t[e] * 0.125f);
      qf[kk] = t;
    }
  };

  auto stageK = [&](int j0, int bufi) {
#pragma unroll
    for (int i = 0; i < 2; ++i) {
      const int off = i * 4096 + wave * 1024 + lane * 16;
      const int jr = off >> 7;
      const int ce = ((off & 127) >> 1) ^ ((jr & 7) << 3);
      gld_lds16(kqv + (size_t)(bT + j0 + jr) * 3072 + hoff + ce,
                &Ks[bufi][i * 2048 + wave * 512]);
    }
  };

  ushort8_t vreg0, vreg1;
  auto vload = [&](int j0) {
    const unsigned short* vp =
        kqv + (size_t)(bT + j0 + (tid & 63)) * 3072 + hoff + 128 + (tid >> 6) * 8;
    vreg0 = *reinterpret_cast<const ushort8_t*>(vp);
    vreg1 = *reinterpret_cast<const ushort8_t*>(vp + 32);
  };
  auto vwrite = [&](int bufi) {
    const int j = tid & 63;
    const int dg = tid >> 6;
#pragma unroll
    for (int e = 0; e < 8; ++e) Vt[bufi][swz(dg * 8 + e, j)] = vreg0[e];
#pragma unroll
    for (int e = 0; e < 8; ++e) Vt[bufi][swz((dg + 4) * 8 + e, j)] = vreg1[e];
  };

  auto compute = [&](const bf16x8 (&qf)[2], f32x4 (&acc_o)[4], float (&mr)[4],
                     float (&lr)[4], int q0t, int j0, bool diag, int cur) {
    f32x4 s[4];
    PRIO(1);
#pragma unroll
    for (int nt = 0; nt < 4; ++nt) {
      f32x4 a = {0.f, 0.f, 0.f, 0.f};
#pragma unroll
      for (int kk = 0; kk < 2; ++kk) {
        const bf16x8 kf = *reinterpret_cast<const bf16x8*>(
            &Ks[cur][swz(nt * 16 + (lane & 15), kk * 32 + (lane >> 4) * 8)]);
        a = __builtin_amdgcn_mfma_f32_16x16x32_bf16(qf[kk], kf, a, 0, 0, 0);
      }
      s[nt] = a;
    }
    PRIO(0);
#pragma unroll
    for (int r = 0; r < 4; ++r) {
      float mx = -1e30f;
      if (diag) {
        const int qg = q0t + wave * 16 + ((lane >> 4) << 2) + r;
#pragma unroll
        for (int nt = 0; nt < 4; ++nt) {
          const int jg = j0 + nt * 16 + (lane & 15);
          const float sv = (jg <= qg) ? s[nt][r] : -1e30f;
          s[nt][r] = sv;
          mx = fmaxf(mx, sv);
        }
      } else {
#pragma unroll
        for (int nt = 0; nt < 4; ++nt) mx = fmaxf(mx, s[nt][r]);
      }
#pragma unroll
      for (int xm = 1; xm < 16; xm <<= 1) mx = fmaxf(mx, __shfl_xor(mx, xm, 64));
      // T13 defer-max: only rescale when some row grew by > THR=8
      if (!__all(mx <= mr[r] + 8.0f)) {
        const float mnew = fmaxf(mr[r], mx);
        const float sc = exp2f((mr[r] - mnew) * LOG2E);
        mr[r] = mnew;
        lr[r] *= sc;
#pragma unroll
        for (int dt = 0; dt < 4; ++dt) acc_o[dt][r] *= sc;
      }
      float ssum = 0.f;
#pragma unroll
      for (int nt = 0; nt < 4; ++nt) {
        const float p = exp2f((s[nt][r] - mr[r]) * LOG2E);
        s[nt][r] = p;
        ssum += p;
      }
#pragma unroll
      for (int xm = 1; xm < 16; xm <<= 1) ssum += __shfl_xor(ssum, xm, 64);
      lr[r] += ssum;
    }
    unsigned short* Pw = &Ps[wave][0];
#pragma unroll
    for (int nt = 0; nt < 4; ++nt)
#pragma unroll
      for (int r = 0; r < 4; ++r)
        Pw[swz(((lane >> 4) << 2) + r, nt * 16 + (lane & 15))] = f2bf_bits(s[nt][r]);
    PRIO(1);
#pragma unroll
    for (int kk = 0; kk < 2; ++kk) {
      const bf16x8 pf = *reinterpret_cast<const bf16x8*>(
          &Ps[wave][swz(lane & 15, kk * 32 + (lane >> 4) * 8)]);
#pragma unroll
      for (int dt = 0; dt < 4; ++dt) {
        const bf16x8 vf = *reinterpret_cast<const bf16x8*>(
            &Vt[cur][swz(dt * 16 + (lane & 15), kk * 32 + (lane >> 4) * 8)]);
        acc_o[dt] = __builtin_amdgcn_mfma_f32_16x16x32_bf16(pf, vf, acc_o[dt], 0, 0, 0);
      }
    }
    PRIO(0);
  };

  auto writeo = [&](int q0t, f32x4 (&acc_o)[4], float (&lr)[4]) {
#pragma unroll
    for (int dt = 0; dt < 4; ++dt)
#pragma unroll
      for (int r = 0; r < 4; ++r) {
        const int qg = q0t + wave * 16 + ((lane >> 4) << 2) + r;
        y[(size_t)(bT + qg) * 1024 + h * 64 + dt * 16 + (lane & 15)] =
            f2bf_bits(acc_o[dt][r] / lr[r]);
      }
  };

  bf16x8 qf_l[2], qf_h[2];
  loadq(lo * 64, qf_l);
  loadq(hi * 64, qf_h);
  f32x4 acc_l[4], acc_h[4];
#pragma unroll
  for (int dt = 0; dt < 4; ++dt) {
    f32x4 z = {0.f, 0.f, 0.f, 0.f};
    acc_l[dt] = z;
    acc_h[dt] = z;
  }
  float mr_l[4] = {-1e30f, -1e30f, -1e30f, -1e30f};
  float mr_h[4] = {-1e30f, -1e30f, -1e30f, -1e30f};
  float lr_l[4] = {0.f, 0.f, 0.f, 0.f};
  float lr_h[4] = {0.f, 0.f, 0.f, 0.f};

  stageK(0, 0);
  vload(0);
  vwrite(0);

  for (int jt = 0; jt <= hi; ++jt) {
    const int cur = jt & 1;
    __syncthreads();  // drains vmcnt/lgkm: buf[cur] ready; buf[cur^1] free
    if (jt < hi) {
      stageK((jt + 1) * 64, cur ^ 1);
      vload((jt + 1) * 64);
    }
    compute(qf_h, acc_h, mr_h, lr_h, hi * 64, jt * 64, jt == hi, cur);
    if (jt <= lo)
      compute(qf_l, acc_l, mr_l, lr_l, lo * 64, jt * 64, jt == lo, cur);
    if (jt < hi) vwrite(cur ^ 1);
  }

  writeo(hi * 64, acc_h, lr_h);
  writeo(lo * 64, acc_l, lr_l);
}

// ---------------- launch ----------------
extern "C" void kernel_launch(void* const* d_in, const int* in_sizes, int n_in,
                              void* d_out, int out_size, void* d_ws, size_t ws_size,
                              hipStream_t stream) {
  const float* x = (const float*)d_in[0];
  const float* kqv_w = (const float*)d_in[1];
  const float* kqv_b = (const float*)d_in[2];
  const float* proj_w = (const float*)d_in[3];
  const float* proj_b = (const float*)d_in[4];
  const float* ln1_g = (const float*)d_in[5];
  const float* ln1_b = (const float*)d_in[6];
  const float* ln2_g = (const float*)d_in[7];
  const float* ln2_b = (const float*)d_in[8];
  const float* fc1_w = (const float*)d_in[9];
  const float* fc1_b = (const float*)d_in[10];
  const float* fc2_w = (const float*)d_in[11];
  const float* fc2_b = (const float*)d_in[12];
  float* out = (float*)d_out;

  char* ws = (char*)d_ws;
  size_t off = 0;
  auto alloc = [&](size_t bytes) {
    char* p = ws + off;
    off += (bytes + 255) & ~(size_t)255;
    return p;
  };
  unsigned short* wk = (unsigned short*)alloc((size_t)3072 * 1024 * 2);
  unsigned short* wp = (unsigned short*)alloc((size_t)1024 * 1024 * 2);
  unsigned short* w1 = (unsigned short*)alloc((size_t)4096 * 1024 * 2);
  unsigned short* w2 = (unsigned short*)alloc((size_t)4096 * 1024 * 2);
  unsigned short* hbuf = (unsigned short*)alloc((size_t)8192 * 1024 * 2);
  unsigned short* kqvb = (unsigned short*)alloc((size_t)8192 * 3072 * 2);
  unsigned short* yb = (unsigned short*)alloc((size_t)8192 * 1024 * 2);
  float* x1 = (float*)alloc((size_t)8192 * 1024 * 4);
  unsigned short* a1 = (unsigned short*)alloc((size_t)8192 * 4096 * 2);

  // cast weights to bf16
  cast_kernel<<<dim3(3072 * 1024 / 1024), 256, 0, stream>>>(kqv_w, wk, 3072 * 1024);
  cast_kernel<<<dim3(1024 * 1024 / 1024), 256, 0, stream>>>(proj_w, wp, 1024 * 1024);
  cast_kernel<<<dim3(4096 * 1024 / 1024), 256, 0, stream>>>(fc1_w, w1, 4096 * 1024);
  cast_kernel<<<dim3(4096 * 1024 / 1024), 256, 0, stream>>>(fc2_w, w2, 4096 * 1024);

  // LN1 -> h (bf16)
  ln_kernel<<<dim3(8192), 256, 0, stream>>>(x, ln1_g, ln1_b, hbuf);

  // kqv = h @ kqv_w^T + b   [8192 x 3072]   grid (24,64)
  gemmS<0, 3072, 1024><<<dim3(3072 / 128, 8192 / 128), 256, 0, stream>>>(
      hbuf, wk, kqv_b, nullptr, kqvb, nullptr);

  // attention -> y (bf16)
  attn_kernel<<<dim3(128, 8), 256, 0, stream>>>(kqvb, yb);

  // x1 = x + y @ proj_w^T + b   (fp32)   grid (8,64)
  gemmS<1, 1024, 1024><<<dim3(1024 / 128, 8192 / 128), 256, 0, stream>>>(
      yb, wp, proj_b, x, nullptr, x1);

  // LN2 -> h (bf16, reuse)
  ln_kernel<<<dim3(8192), 256, 0, stream>>>(x1, ln2_g, ln2_b, hbuf);

  // a1 = gelu(h @ fc1_w^T + b)  [8192 x 4096]   grid (32,64)
  gemmS<2, 4096, 1024><<<dim3(4096 / 128, 8192 / 128), 256, 0, stream>>>(
      hbuf, w1, fc1_b, nullptr, a1, nullptr);

  // out = x1 + a1 @ fc2_w^T + b  (fp32)  grid (8,64), K=4096
  gemmS<1, 1024, 4096><<<dim3(1024 / 128, 8192 / 128), 256, 0, stream>>>(
      a1, w2, fc2_b, x1, nullptr, out);
}

// Round 18
// 427.763 us; speedup vs baseline: 1.4513x; 1.4513x over previous
//
#include <hip/hip_runtime.h>
#include <math.h>
#include <stdint.h>

typedef __bf16 bf16_t;
typedef __bf16 bf16x8 __attribute__((ext_vector_type(8)));
typedef float f32x4 __attribute__((ext_vector_type(4)));
typedef unsigned short ushort8_t __attribute__((ext_vector_type(8)));
typedef unsigned short ushort4_t __attribute__((ext_vector_type(4)));

#define LOG2E 1.44269504088896340736f
#define PRIO(p) __builtin_amdgcn_s_setprio(p)

__device__ inline unsigned short f2bf_bits(float f) {
  union { float f; unsigned int u; } v; v.f = f;
  unsigned int u = v.u;
  return (unsigned short)((u + 0x7fffu + ((u >> 16) & 1u)) >> 16);
}

// global -> LDS direct copy, 16B per lane. LDS dest is wave-uniform base
// + lane*16 (HW behavior, m104); global src is per-lane.
__device__ inline void gld_lds16(const void* g, void* l) {
  __builtin_amdgcn_global_load_lds(
      (__attribute__((address_space(1))) void*)(uintptr_t)(g),
      (__attribute__((address_space(3))) void*)(uintptr_t)(l),
      16, 0, 0);
}

// ---------------- cast fp32 -> bf16 (weights) ----------------
__global__ __launch_bounds__(256) void cast_kernel(const float* __restrict__ in,
                                                   unsigned short* __restrict__ out,
                                                   int n) {
  int i = (blockIdx.x * 256 + threadIdx.x) * 4;
  if (i >= n) return;
  float4 f = *reinterpret_cast<const float4*>(in + i);
  ushort4_t o;
  o[0] = f2bf_bits(f.x); o[1] = f2bf_bits(f.y);
  o[2] = f2bf_bits(f.z); o[3] = f2bf_bits(f.w);
  *reinterpret_cast<ushort4_t*>(out + i) = o;
}

// ---------------- LayerNorm (C=1024) + cast to bf16 ----------------
__global__ __launch_bounds__(256) void ln_kernel(const float* __restrict__ x,
                                                 const float* __restrict__ g,
                                                 const float* __restrict__ bta,
                                                 unsigned short* __restrict__ out) {
  const int row = blockIdx.x;
  const int c = threadIdx.x * 4;
  const float4 xv = *reinterpret_cast<const float4*>(x + (size_t)row * 1024 + c);
  float s = xv.x + xv.y + xv.z + xv.w;
  float sq = xv.x * xv.x + xv.y * xv.y + xv.z * xv.z + xv.w * xv.w;
#pragma unroll
  for (int xm = 1; xm < 64; xm <<= 1) {
    s += __shfl_xor(s, xm, 64);
    sq += __shfl_xor(sq, xm, 64);
  }
  __shared__ float sh[8];
  const int wave = threadIdx.x >> 6, lane = threadIdx.x & 63;
  if (lane == 0) { sh[wave] = s; sh[4 + wave] = sq; }
  __syncthreads();
  const float ts = sh[0] + sh[1] + sh[2] + sh[3];
  const float tq = sh[4] + sh[5] + sh[6] + sh[7];
  const float mean = ts * (1.0f / 1024.0f);
  const float var = tq * (1.0f / 1024.0f) - mean * mean;
  const float rstd = rsqrtf(var + 1e-5f);
  const float4 gv = *reinterpret_cast<const float4*>(g + c);
  const float4 bv = *reinterpret_cast<const float4*>(bta + c);
  ushort4_t o;
  o[0] = f2bf_bits((xv.x - mean) * rstd * gv.x + bv.x);
  o[1] = f2bf_bits((xv.y - mean) * rstd * gv.y + bv.y);
  o[2] = f2bf_bits((xv.z - mean) * rstd * gv.z + bv.z);
  o[3] = f2bf_bits((xv.w - mean) * rstd * gv.w + bv.w);
  *reinterpret_cast<ushort4_t*>(out + (size_t)row * 1024 + c) = o;
}

// ---------------- GEMM m97-build-replica (R16, FROZEN) ----------------------
// Best measured GEMM config (R16: fc1 102us / 674 TF, MfmaUtil 31%, 0
// conflicts): 128^2 tile, 4 waves, BK=64, single 32KiB LDS, plain
// __syncthreads, NO launch_bounds (allocator freedom — SAFE HERE: live state
// ~60 regs; NOT safe on attn, see R17 post-mortem), compile-time N/K.
template <int EPI, int NN, int KK>  // EPI: 0 bias->bf16; 1 bias+res->f32; 2 bias+GELU->bf16
__global__ void gemmS(const unsigned short* __restrict__ A,
                      const unsigned short* __restrict__ W,
                      const float* __restrict__ bias,
                      const float* __restrict__ res,
                      unsigned short* __restrict__ outb,
                      float* __restrict__ outf) {
  __shared__ unsigned short lds[2 * 128 * 64];  // 32 KiB: A then B
  const int tid = threadIdx.x;
  const int wave = tid >> 6, l = tid & 63;
  const int m0 = blockIdx.y * 128, n0 = blockIdx.x * 128;
  const int wm = wave >> 1, wn = wave & 1;   // 2x2 wave grid
  const int lr16 = l & 15, lk = l >> 4;
  const int axor = (lr16 & 7) << 3;          // read-side XOR (row&7 == lr16&7)
  const int B0 = 128 * 64;

  const int sr = tid >> 3;
  const int sx = ((tid & 7) ^ (sr & 7)) << 3;

  f32x4 acc[4][4];
#pragma unroll
  for (int i = 0; i < 4; ++i)
#pragma unroll
    for (int j = 0; j < 4; ++j) { f32x4 z = {0.f, 0.f, 0.f, 0.f}; acc[i][j] = z; }

  const int nt = KK / 64;
  for (int t = 0; t < nt; ++t) {
#pragma unroll
    for (int h = 0; h < 4; ++h)
      gld_lds16(A + (size_t)(m0 + h * 32 + sr) * KK + t * 64 + sx,
                &lds[h * 2048 + tid * 8]);
#pragma unroll
    for (int h = 0; h < 4; ++h)
      gld_lds16(W + (size_t)(n0 + h * 32 + sr) * KK + t * 64 + sx,
                &lds[B0 + h * 2048 + tid * 8]);
    __syncthreads();  // compiler emits the vmcnt/lgkm drain here

    bf16x8 af0[4], af1[4];
#pragma unroll
    for (int mi = 0; mi < 4; ++mi) {
      const int arow = (wm * 64 + mi * 16 + lr16) * 64;
      af0[mi] = *reinterpret_cast<const bf16x8*>(&lds[arow + ((lk * 8) ^ axor)]);
      af1[mi] = *reinterpret_cast<const bf16x8*>(&lds[arow + ((32 + lk * 8) ^ axor)]);
    }
#pragma unroll
    for (int ni = 0; ni < 4; ++ni) {
      const int brow = (wn * 64 + ni * 16 + lr16) * 64;
      const bf16x8 b0 = *reinterpret_cast<const bf16x8*>(
          &lds[B0 + brow + ((lk * 8) ^ axor)]);
      const bf16x8 b1 = *reinterpret_cast<const bf16x8*>(
          &lds[B0 + brow + ((32 + lk * 8) ^ axor)]);
#pragma unroll
      for (int mi = 0; mi < 4; ++mi) {
        acc[mi][ni] =
            __builtin_amdgcn_mfma_f32_16x16x32_bf16(af0[mi], b0, acc[mi][ni], 0, 0, 0);
        acc[mi][ni] =
            __builtin_amdgcn_mfma_f32_16x16x32_bf16(af1[mi], b1, acc[mi][ni], 0, 0, 0);
      }
    }
    __syncthreads();  // all reads done before next tile's gld_lds overwrites
  }

  // epilogue: C row=(l>>4)*4+r, col=l&15 per 16x16 fragment (m89/m91)
#pragma unroll
  for (int ni = 0; ni < 4; ++ni) {
    const int col = n0 + wn * 64 + ni * 16 + lr16;
    const float bv = bias[col];
#pragma unroll
    for (int mi = 0; mi < 4; ++mi) {
#pragma unroll
      for (int r = 0; r < 4; ++r) {
        const int row = m0 + wm * 64 + mi * 16 + lk * 4 + r;
        const size_t idx = (size_t)row * NN + col;
        float v = acc[mi][ni][r] + bv;
        if (EPI == 0) {
          outb[idx] = f2bf_bits(v);
        } else if (EPI == 1) {
          outf[idx] = v + res[idx];
        } else {
          v = 0.5f * v * (1.0f + erff(v * 0.70710678118654752f));
          outb[idx] = f2bf_bits(v);
        }
      }
    }
  }
}

// ---------------- causal flash attention v3 (R18) ---------------------------
// R17 post-mortem: removing launch_bounds(256) from THIS kernel -> allocator
// targeted 64-reg budget, spilled ~110 live regs (FETCH 547MB, WRITE 396MB,
// 257us). Allocator freedom is only safe when live state < default budget
// (gemmS ~60 regs yes; attn ~110+ no). R18 = R17 with launch_bounds(256)
// RESTORED — clean A/B for the two catalog levers kept:
//  (a) T5 setprio(1) around QK^T and PV MFMA clusters (+4-7% attn, m191).
//  (b) T13 defer-max THR=8: skip O-rescale + m-update when
//      __all(mx - m <= 8); P bounded by e^8 (bf16/f32 safe, m214).
__device__ inline int swz(int row, int colelem) {
  return row * 64 + (colelem ^ ((row & 7) << 3));
}

__global__ __launch_bounds__(256) void attn_kernel(const unsigned short* __restrict__ kqv,
                                                   unsigned short* __restrict__ y) {
  __shared__ unsigned short Ks[2][64 * 64];
  __shared__ unsigned short Vt[2][64 * 64];
  __shared__ unsigned short Ps[4][16 * 64];

  const int tid = threadIdx.x;
  const int wave = tid >> 6;
  const int lane = tid & 63;
  const int bh = blockIdx.x;
  const int pair = blockIdx.y;
  const int b = bh >> 4;
  const int h = bh & 15;
  const int lo = pair;
  const int hi = 15 - pair;
  const int bT = b * 1024;
  const int hoff = h * 192;

  auto loadq = [&](int q0t, bf16x8 (&qf)[2]) {
    const unsigned short* qp =
        kqv + (size_t)(bT + q0t + wave * 16 + (lane & 15)) * 3072 + hoff + 64 +
        (lane >> 4) * 8;
#pragma unroll
    for (int kk = 0; kk < 2; ++kk) {
      bf16x8 t = *reinterpret_cast<const bf16x8*>(qp + kk * 32);
#pragma unroll
      for (int e = 0; e < 8; ++e) t[e] = (bf16_t)((float)t[e] * 0.125f);
      qf[kk] = t;
    }
  };

  auto stageK = [&](int j0, int bufi) {
#pragma unroll
    for (int i = 0; i < 2; ++i) {
      const int off = i * 4096 + wave * 1024 + lane * 16;
      const int jr = off >> 7;
      const int ce = ((off & 127) >> 1) ^ ((jr & 7) << 3);
      gld_lds16(kqv + (size_t)(bT + j0 + jr) * 3072 + hoff + ce,
                &Ks[bufi][i * 2048 + wave * 512]);
    }
  };

  ushort8_t vreg0, vreg1;
  auto vload = [&](int j0) {
    const unsigned short* vp =
        kqv + (size_t)(bT + j0 + (tid & 63)) * 3072 + hoff + 128 + (tid >> 6) * 8;
    vreg0 = *reinterpret_cast<const ushort8_t*>(vp);
    vreg1 = *reinterpret_cast<const ushort8_t*>(vp + 32);
  };
  auto vwrite = [&](int bufi) {
    const int j = tid & 63;
    const int dg = tid >> 6;
#pragma unroll
    for (int e = 0; e < 8; ++e) Vt[bufi][swz(dg * 8 + e, j)] = vreg0[e];
#pragma unroll
    for (int e = 0; e < 8; ++e) Vt[bufi][swz((dg + 4) * 8 + e, j)] = vreg1[e];
  };

  auto compute = [&](const bf16x8 (&qf)[2], f32x4 (&acc_o)[4], float (&mr)[4],
                     float (&lr)[4], int q0t, int j0, bool diag, int cur) {
    f32x4 s[4];
    PRIO(1);
#pragma unroll
    for (int nt = 0; nt < 4; ++nt) {
      f32x4 a = {0.f, 0.f, 0.f, 0.f};
#pragma unroll
      for (int kk = 0; kk < 2; ++kk) {
        const bf16x8 kf = *reinterpret_cast<const bf16x8*>(
            &Ks[cur][swz(nt * 16 + (lane & 15), kk * 32 + (lane >> 4) * 8)]);
        a = __builtin_amdgcn_mfma_f32_16x16x32_bf16(qf[kk], kf, a, 0, 0, 0);
      }
      s[nt] = a;
    }
    PRIO(0);
#pragma unroll
    for (int r = 0; r < 4; ++r) {
      float mx = -1e30f;
      if (diag) {
        const int qg = q0t + wave * 16 + ((lane >> 4) << 2) + r;
#pragma unroll
        for (int nt = 0; nt < 4; ++nt) {
          const int jg = j0 + nt * 16 + (lane & 15);
          const float sv = (jg <= qg) ? s[nt][r] : -1e30f;
          s[nt][r] = sv;
          mx = fmaxf(mx, sv);
        }
      } else {
#pragma unroll
        for (int nt = 0; nt < 4; ++nt) mx = fmaxf(mx, s[nt][r]);
      }
#pragma unroll
      for (int xm = 1; xm < 16; xm <<= 1) mx = fmaxf(mx, __shfl_xor(mx, xm, 64));
      // T13 defer-max: only rescale when some row grew by > THR=8
      if (!__all(mx <= mr[r] + 8.0f)) {
        const float mnew = fmaxf(mr[r], mx);
        const float sc = exp2f((mr[r] - mnew) * LOG2E);
        mr[r] = mnew;
        lr[r] *= sc;
#pragma unroll
        for (int dt = 0; dt < 4; ++dt) acc_o[dt][r] *= sc;
      }
      float ssum = 0.f;
#pragma unroll
      for (int nt = 0; nt < 4; ++nt) {
        const float p = exp2f((s[nt][r] - mr[r]) * LOG2E);
        s[nt][r] = p;
        ssum += p;
      }
#pragma unroll
      for (int xm = 1; xm < 16; xm <<= 1) ssum += __shfl_xor(ssum, xm, 64);
      lr[r] += ssum;
    }
    unsigned short* Pw = &Ps[wave][0];
#pragma unroll
    for (int nt = 0; nt < 4; ++nt)
#pragma unroll
      for (int r = 0; r < 4; ++r)
        Pw[swz(((lane >> 4) << 2) + r, nt * 16 + (lane & 15))] = f2bf_bits(s[nt][r]);
    PRIO(1);
#pragma unroll
    for (int kk = 0; kk < 2; ++kk) {
      const bf16x8 pf = *reinterpret_cast<const bf16x8*>(
          &Ps[wave][swz(lane & 15, kk * 32 + (lane >> 4) * 8)]);
#pragma unroll
      for (int dt = 0; dt < 4; ++dt) {
        const bf16x8 vf = *reinterpret_cast<const bf16x8*>(
            &Vt[cur][swz(dt * 16 + (lane & 15), kk * 32 + (lane >> 4) * 8)]);
        acc_o[dt] = __builtin_amdgcn_mfma_f32_16x16x32_bf16(pf, vf, acc_o[dt], 0, 0, 0);
      }
    }
    PRIO(0);
  };

  auto writeo = [&](int q0t, f32x4 (&acc_o)[4], float (&lr)[4]) {
#pragma unroll
    for (int dt = 0; dt < 4; ++dt)
#pragma unroll
      for (int r = 0; r < 4; ++r) {
        const int qg = q0t + wave * 16 + ((lane >> 4) << 2) + r;
        y[(size_t)(bT + qg) * 1024 + h * 64 + dt * 16 + (lane & 15)] =
            f2bf_bits(acc_o[dt][r] / lr[r]);
      }
  };

  bf16x8 qf_l[2], qf_h[2];
  loadq(lo * 64, qf_l);
  loadq(hi * 64, qf_h);
  f32x4 acc_l[4], acc_h[4];
#pragma unroll
  for (int dt = 0; dt < 4; ++dt) {
    f32x4 z = {0.f, 0.f, 0.f, 0.f};
    acc_l[dt] = z;
    acc_h[dt] = z;
  }
  float mr_l[4] = {-1e30f, -1e30f, -1e30f, -1e30f};
  float mr_h[4] = {-1e30f, -1e30f, -1e30f, -1e30f};
  float lr_l[4] = {0.f, 0.f, 0.f, 0.f};
  float lr_h[4] = {0.f, 0.f, 0.f, 0.f};

  stageK(0, 0);
  vload(0);
  vwrite(0);

  for (int jt = 0; jt <= hi; ++jt) {
    const int cur = jt & 1;
    __syncthreads();  // drains vmcnt/lgkm: buf[cur] ready; buf[cur^1] free
    if (jt < hi) {
      stageK((jt + 1) * 64, cur ^ 1);
      vload((jt + 1) * 64);
    }
    compute(qf_h, acc_h, mr_h, lr_h, hi * 64, jt * 64, jt == hi, cur);
    if (jt <= lo)
      compute(qf_l, acc_l, mr_l, lr_l, lo * 64, jt * 64, jt == lo, cur);
    if (jt < hi) vwrite(cur ^ 1);
  }

  writeo(hi * 64, acc_h, lr_h);
  writeo(lo * 64, acc_l, lr_l);
}

// ---------------- launch ----------------
extern "C" void kernel_launch(void* const* d_in, const int* in_sizes, int n_in,
                              void* d_out, int out_size, void* d_ws, size_t ws_size,
                              hipStream_t stream) {
  const float* x = (const float*)d_in[0];
  const float* kqv_w = (const float*)d_in[1];
  const float* kqv_b = (const float*)d_in[2];
  const float* proj_w = (const float*)d_in[3];
  const float* proj_b = (const float*)d_in[4];
  const float* ln1_g = (const float*)d_in[5];
  const float* ln1_b = (const float*)d_in[6];
  const float* ln2_g = (const float*)d_in[7];
  const float* ln2_b = (const float*)d_in[8];
  const float* fc1_w = (const float*)d_in[9];
  const float* fc1_b = (const float*)d_in[10];
  const float* fc2_w = (const float*)d_in[11];
  const float* fc2_b = (const float*)d_in[12];
  float* out = (float*)d_out;

  char* ws = (char*)d_ws;
  size_t off = 0;
  auto alloc = [&](size_t bytes) {
    char* p = ws + off;
    off += (bytes + 255) & ~(size_t)255;
    return p;
  };
  unsigned short* wk = (unsigned short*)alloc((size_t)3072 * 1024 * 2);
  unsigned short* wp = (unsigned short*)alloc((size_t)1024 * 1024 * 2);
  unsigned short* w1 = (unsigned short*)alloc((size_t)4096 * 1024 * 2);
  unsigned short* w2 = (unsigned short*)alloc((size_t)4096 * 1024 * 2);
  unsigned short* hbuf = (unsigned short*)alloc((size_t)8192 * 1024 * 2);
  unsigned short* kqvb = (unsigned short*)alloc((size_t)8192 * 3072 * 2);
  unsigned short* yb = (unsigned short*)alloc((size_t)8192 * 1024 * 2);
  float* x1 = (float*)alloc((size_t)8192 * 1024 * 4);
  unsigned short* a1 = (unsigned short*)alloc((size_t)8192 * 4096 * 2);

  // cast weights to bf16
  cast_kernel<<<dim3(3072 * 1024 / 1024), 256, 0, stream>>>(kqv_w, wk, 3072 * 1024);
  cast_kernel<<<dim3(1024 * 1024 / 1024), 256, 0, stream>>>(proj_w, wp, 1024 * 1024);
  cast_kernel<<<dim3(4096 * 1024 / 1024), 256, 0, stream>>>(fc1_w, w1, 4096 * 1024);
  cast_kernel<<<dim3(4096 * 1024 / 1024), 256, 0, stream>>>(fc2_w, w2, 4096 * 1024);

  // LN1 -> h (bf16)
  ln_kernel<<<dim3(8192), 256, 0, stream>>>(x, ln1_g, ln1_b, hbuf);

  // kqv = h @ kqv_w^T + b   [8192 x 3072]   grid (24,64)
  gemmS<0, 3072, 1024><<<dim3(3072 / 128, 8192 / 128), 256, 0, stream>>>(
      hbuf, wk, kqv_b, nullptr, kqvb, nullptr);

  // attention -> y (bf16)
  attn_kernel<<<dim3(128, 8), 256, 0, stream>>>(kqvb, yb);

  // x1 = x + y @ proj_w^T + b   (fp32)   grid (8,64)
  gemmS<1, 1024, 1024><<<dim3(1024 / 128, 8192 / 128), 256, 0, stream>>>(
      yb, wp, proj_b, x, nullptr, x1);

  // LN2 -> h (bf16, reuse)
  ln_kernel<<<dim3(8192), 256, 0, stream>>>(x1, ln2_g, ln2_b, hbuf);

  // a1 = gelu(h @ fc1_w^T + b)  [8192 x 4096]   grid (32,64)
  gemmS<2, 4096, 1024><<<dim3(4096 / 128, 8192 / 128), 256, 0, stream>>>(
      hbuf, w1, fc1_b, nullptr, a1, nullptr);

  // out = x1 + a1 @ fc2_w^T + b  (fp32)  grid (8,64), K=4096
  gemmS<1, 1024, 4096><<<dim3(1024 / 128, 8192 / 128), 256, 0, stream>>>(
      a1, w2, fc2_b, x1, nullptr, out);
}

// Round 19
// 416.590 us; speedup vs baseline: 1.4902x; 1.0268x over previous
//
#include <hip/hip_runtime.h>
#include <math.h>
#include <stdint.h>

typedef __bf16 bf16_t;
typedef __bf16 bf16x8 __attribute__((ext_vector_type(8)));
typedef float f32x4 __attribute__((ext_vector_type(4)));
typedef unsigned short ushort8_t __attribute__((ext_vector_type(8)));
typedef unsigned short ushort4_t __attribute__((ext_vector_type(4)));

#define LOG2E 1.44269504088896340736f

__device__ inline unsigned short f2bf_bits(float f) {
  union { float f; unsigned int u; } v; v.f = f;
  unsigned int u = v.u;
  return (unsigned short)((u + 0x7fffu + ((u >> 16) & 1u)) >> 16);
}

// global -> LDS direct copy, 16B per lane. LDS dest is wave-uniform base
// + lane*16 (HW behavior, m104); global src is per-lane.
__device__ inline void gld_lds16(const void* g, void* l) {
  __builtin_amdgcn_global_load_lds(
      (__attribute__((address_space(1))) void*)(uintptr_t)(g),
      (__attribute__((address_space(3))) void*)(uintptr_t)(l),
      16, 0, 0);
}

// ---------------- fused cast fp32 -> bf16 (all 4 weights, one launch) -------
// Segment boundaries are multiples of the 1024-elem block span -> the
// segment branch is block-uniform (no divergence). Saves 3 dispatches.
__global__ __launch_bounds__(256) void cast4_kernel(
    const float* __restrict__ w0, const float* __restrict__ w1,
    const float* __restrict__ w2, const float* __restrict__ w3,
    unsigned short* __restrict__ o0, unsigned short* __restrict__ o1,
    unsigned short* __restrict__ o2, unsigned short* __restrict__ o3) {
  int i = (blockIdx.x * 256 + threadIdx.x) * 4;
  const float* src;
  unsigned short* dst;
  int off;
  if (i < 3145728) {               // kqv_w: 3072*1024
    src = w0; dst = o0; off = i;
  } else if (i < 4194304) {        // proj_w: +1024*1024
    src = w1; dst = o1; off = i - 3145728;
  } else if (i < 8388608) {        // fc1_w: +4096*1024
    src = w2; dst = o2; off = i - 4194304;
  } else {                         // fc2_w: +4096*1024 (total 12582912)
    src = w3; dst = o3; off = i - 8388608;
  }
  float4 f = *reinterpret_cast<const float4*>(src + off);
  ushort4_t o;
  o[0] = f2bf_bits(f.x); o[1] = f2bf_bits(f.y);
  o[2] = f2bf_bits(f.z); o[3] = f2bf_bits(f.w);
  *reinterpret_cast<ushort4_t*>(dst + off) = o;
}

// ---------------- LayerNorm (C=1024) + cast to bf16 ----------------
__global__ __launch_bounds__(256) void ln_kernel(const float* __restrict__ x,
                                                 const float* __restrict__ g,
                                                 const float* __restrict__ bta,
                                                 unsigned short* __restrict__ out) {
  const int row = blockIdx.x;
  const int c = threadIdx.x * 4;
  const float4 xv = *reinterpret_cast<const float4*>(x + (size_t)row * 1024 + c);
  float s = xv.x + xv.y + xv.z + xv.w;
  float sq = xv.x * xv.x + xv.y * xv.y + xv.z * xv.z + xv.w * xv.w;
#pragma unroll
  for (int xm = 1; xm < 64; xm <<= 1) {
    s += __shfl_xor(s, xm, 64);
    sq += __shfl_xor(sq, xm, 64);
  }
  __shared__ float sh[8];
  const int wave = threadIdx.x >> 6, lane = threadIdx.x & 63;
  if (lane == 0) { sh[wave] = s; sh[4 + wave] = sq; }
  __syncthreads();
  const float ts = sh[0] + sh[1] + sh[2] + sh[3];
  const float tq = sh[4] + sh[5] + sh[6] + sh[7];
  const float mean = ts * (1.0f / 1024.0f);
  const float var = tq * (1.0f / 1024.0f) - mean * mean;
  const float rstd = rsqrtf(var + 1e-5f);
  const float4 gv = *reinterpret_cast<const float4*>(g + c);
  const float4 bv = *reinterpret_cast<const float4*>(bta + c);
  ushort4_t o;
  o[0] = f2bf_bits((xv.x - mean) * rstd * gv.x + bv.x);
  o[1] = f2bf_bits((xv.y - mean) * rstd * gv.y + bv.y);
  o[2] = f2bf_bits((xv.z - mean) * rstd * gv.z + bv.z);
  o[3] = f2bf_bits((xv.w - mean) * rstd * gv.w + bv.w);
  *reinterpret_cast<ushort4_t*>(out + (size_t)row * 1024 + c) = o;
}

// ---------------- GEMM m97-build-replica (R16, FROZEN) ----------------------
// Best measured GEMM config (R16: fc1 102us / 674 TF, MfmaUtil 31%, 0
// conflicts, occupancy 38.7%): 128^2 tile, 4 waves, BK=64, single 32KiB LDS,
// plain __syncthreads, NO launch_bounds (allocator freedom — safe here: live
// state ~60 regs; NOT safe on attn, R17 post-mortem), compile-time N/K.
// Structural search exhausted (R8-R15: 8 variants all 520-680 TF).
template <int EPI, int NN, int KK>  // EPI: 0 bias->bf16; 1 bias+res->f32; 2 bias+GELU->bf16
__global__ void gemmS(const unsigned short* __restrict__ A,
                      const unsigned short* __restrict__ W,
                      const float* __restrict__ bias,
                      const float* __restrict__ res,
                      unsigned short* __restrict__ outb,
                      float* __restrict__ outf) {
  __shared__ unsigned short lds[2 * 128 * 64];  // 32 KiB: A then B
  const int tid = threadIdx.x;
  const int wave = tid >> 6, l = tid & 63;
  const int m0 = blockIdx.y * 128, n0 = blockIdx.x * 128;
  const int wm = wave >> 1, wn = wave & 1;   // 2x2 wave grid
  const int lr16 = l & 15, lk = l >> 4;
  const int axor = (lr16 & 7) << 3;          // read-side XOR (row&7 == lr16&7)
  const int B0 = 128 * 64;

  const int sr = tid >> 3;
  const int sx = ((tid & 7) ^ (sr & 7)) << 3;

  f32x4 acc[4][4];
#pragma unroll
  for (int i = 0; i < 4; ++i)
#pragma unroll
    for (int j = 0; j < 4; ++j) { f32x4 z = {0.f, 0.f, 0.f, 0.f}; acc[i][j] = z; }

  const int nt = KK / 64;
  for (int t = 0; t < nt; ++t) {
#pragma unroll
    for (int h = 0; h < 4; ++h)
      gld_lds16(A + (size_t)(m0 + h * 32 + sr) * KK + t * 64 + sx,
                &lds[h * 2048 + tid * 8]);
#pragma unroll
    for (int h = 0; h < 4; ++h)
      gld_lds16(W + (size_t)(n0 + h * 32 + sr) * KK + t * 64 + sx,
                &lds[B0 + h * 2048 + tid * 8]);
    __syncthreads();  // compiler emits the vmcnt/lgkm drain here

    bf16x8 af0[4], af1[4];
#pragma unroll
    for (int mi = 0; mi < 4; ++mi) {
      const int arow = (wm * 64 + mi * 16 + lr16) * 64;
      af0[mi] = *reinterpret_cast<const bf16x8*>(&lds[arow + ((lk * 8) ^ axor)]);
      af1[mi] = *reinterpret_cast<const bf16x8*>(&lds[arow + ((32 + lk * 8) ^ axor)]);
    }
#pragma unroll
    for (int ni = 0; ni < 4; ++ni) {
      const int brow = (wn * 64 + ni * 16 + lr16) * 64;
      const bf16x8 b0 = *reinterpret_cast<const bf16x8*>(
          &lds[B0 + brow + ((lk * 8) ^ axor)]);
      const bf16x8 b1 = *reinterpret_cast<const bf16x8*>(
          &lds[B0 + brow + ((32 + lk * 8) ^ axor)]);
#pragma unroll
      for (int mi = 0; mi < 4; ++mi) {
        acc[mi][ni] =
            __builtin_amdgcn_mfma_f32_16x16x32_bf16(af0[mi], b0, acc[mi][ni], 0, 0, 0);
        acc[mi][ni] =
            __builtin_amdgcn_mfma_f32_16x16x32_bf16(af1[mi], b1, acc[mi][ni], 0, 0, 0);
      }
    }
    __syncthreads();  // all reads done before next tile's gld_lds overwrites
  }

  // epilogue: C row=(l>>4)*4+r, col=l&15 per 16x16 fragment (m89/m91)
#pragma unroll
  for (int ni = 0; ni < 4; ++ni) {
    const int col = n0 + wn * 64 + ni * 16 + lr16;
    const float bv = bias[col];
#pragma unroll
    for (int mi = 0; mi < 4; ++mi) {
#pragma unroll
      for (int r = 0; r < 4; ++r) {
        const int row = m0 + wm * 64 + mi * 16 + lk * 4 + r;
        const size_t idx = (size_t)row * NN + col;
        float v = acc[mi][ni][r] + bv;
        if (EPI == 0) {
          outb[idx] = f2bf_bits(v);
        } else if (EPI == 1) {
          outf[idx] = v + res[idx];
        } else {
          v = 0.5f * v * (1.0f + erff(v * 0.70710678118654752f));
          outb[idx] = f2bf_bits(v);
        }
      }
    }
  }
}

// ---------------- causal flash attention (R16 version, FROZEN) --------------
// R18 A/B verdict: T5 setprio + T13 defer-max = -4.6% on this structure
// (102.1 -> 106.9us) — reverted. launch_bounds(256) REQUIRED (R17: removing
// it -> 64-reg budget -> ~110 regs spilled, 2.5x slower). Paired q-tiles
// (lo=pair, hi=15-pair): uniform 17 compute-iters/block, zero causal tail;
// dbuf K/V; XOR swizzle (0 conflicts).
__device__ inline int swz(int row, int colelem) {
  return row * 64 + (colelem ^ ((row & 7) << 3));
}

__global__ __launch_bounds__(256) void attn_kernel(const unsigned short* __restrict__ kqv,
                                                   unsigned short* __restrict__ y) {
  __shared__ unsigned short Ks[2][64 * 64];
  __shared__ unsigned short Vt[2][64 * 64];
  __shared__ unsigned short Ps[4][16 * 64];

  const int tid = threadIdx.x;
  const int wave = tid >> 6;
  const int lane = tid & 63;
  const int bh = blockIdx.x;
  const int pair = blockIdx.y;
  const int b = bh >> 4;
  const int h = bh & 15;
  const int lo = pair;
  const int hi = 15 - pair;
  const int bT = b * 1024;
  const int hoff = h * 192;

  auto loadq = [&](int q0t, bf16x8 (&qf)[2]) {
    const unsigned short* qp =
        kqv + (size_t)(bT + q0t + wave * 16 + (lane & 15)) * 3072 + hoff + 64 +
        (lane >> 4) * 8;
#pragma unroll
    for (int kk = 0; kk < 2; ++kk) {
      bf16x8 t = *reinterpret_cast<const bf16x8*>(qp + kk * 32);
#pragma unroll
      for (int e = 0; e < 8; ++e) t[e] = (bf16_t)((float)t[e] * 0.125f);
      qf[kk] = t;
    }
  };

  auto stageK = [&](int j0, int bufi) {
#pragma unroll
    for (int i = 0; i < 2; ++i) {
      const int off = i * 4096 + wave * 1024 + lane * 16;
      const int jr = off >> 7;
      const int ce = ((off & 127) >> 1) ^ ((jr & 7) << 3);
      gld_lds16(kqv + (size_t)(bT + j0 + jr) * 3072 + hoff + ce,
                &Ks[bufi][i * 2048 + wave * 512]);
    }
  };

  ushort8_t vreg0, vreg1;
  auto vload = [&](int j0) {
    const unsigned short* vp =
        kqv + (size_t)(bT + j0 + (tid & 63)) * 3072 + hoff + 128 + (tid >> 6) * 8;
    vreg0 = *reinterpret_cast<const ushort8_t*>(vp);
    vreg1 = *reinterpret_cast<const ushort8_t*>(vp + 32);
  };
  auto vwrite = [&](int bufi) {
    const int j = tid & 63;
    const int dg = tid >> 6;
#pragma unroll
    for (int e = 0; e < 8; ++e) Vt[bufi][swz(dg * 8 + e, j)] = vreg0[e];
#pragma unroll
    for (int e = 0; e < 8; ++e) Vt[bufi][swz((dg + 4) * 8 + e, j)] = vreg1[e];
  };

  auto compute = [&](const bf16x8 (&qf)[2], f32x4 (&acc_o)[4], float (&mr)[4],
                     float (&lr)[4], int q0t, int j0, bool diag, int cur) {
    f32x4 s[4];
#pragma unroll
    for (int nt = 0; nt < 4; ++nt) {
      f32x4 a = {0.f, 0.f, 0.f, 0.f};
#pragma unroll
      for (int kk = 0; kk < 2; ++kk) {
        const bf16x8 kf = *reinterpret_cast<const bf16x8*>(
            &Ks[cur][swz(nt * 16 + (lane & 15), kk * 32 + (lane >> 4) * 8)]);
        a = __builtin_amdgcn_mfma_f32_16x16x32_bf16(qf[kk], kf, a, 0, 0, 0);
      }
      s[nt] = a;
    }
#pragma unroll
    for (int r = 0; r < 4; ++r) {
      float mx = -1e30f;
      if (diag) {
        const int qg = q0t + wave * 16 + ((lane >> 4) << 2) + r;
#pragma unroll
        for (int nt = 0; nt < 4; ++nt) {
          const int jg = j0 + nt * 16 + (lane & 15);
          const float sv = (jg <= qg) ? s[nt][r] : -1e30f;
          s[nt][r] = sv;
          mx = fmaxf(mx, sv);
        }
      } else {
#pragma unroll
        for (int nt = 0; nt < 4; ++nt) mx = fmaxf(mx, s[nt][r]);
      }
#pragma unroll
      for (int xm = 1; xm < 16; xm <<= 1) mx = fmaxf(mx, __shfl_xor(mx, xm, 64));
      const float mnew = fmaxf(mr[r], mx);
      const float sc = exp2f((mr[r] - mnew) * LOG2E);
      mr[r] = mnew;
      float ssum = 0.f;
#pragma unroll
      for (int nt = 0; nt < 4; ++nt) {
        const float p = exp2f((s[nt][r] - mnew) * LOG2E);
        s[nt][r] = p;
        ssum += p;
      }
#pragma unroll
      for (int xm = 1; xm < 16; xm <<= 1) ssum += __shfl_xor(ssum, xm, 64);
      lr[r] = lr[r] * sc + ssum;
#pragma unroll
      for (int dt = 0; dt < 4; ++dt) acc_o[dt][r] *= sc;
    }
    unsigned short* Pw = &Ps[wave][0];
#pragma unroll
    for (int nt = 0; nt < 4; ++nt)
#pragma unroll
      for (int r = 0; r < 4; ++r)
        Pw[swz(((lane >> 4) << 2) + r, nt * 16 + (lane & 15))] = f2bf_bits(s[nt][r]);
#pragma unroll
    for (int kk = 0; kk < 2; ++kk) {
      const bf16x8 pf = *reinterpret_cast<const bf16x8*>(
          &Ps[wave][swz(lane & 15, kk * 32 + (lane >> 4) * 8)]);
#pragma unroll
      for (int dt = 0; dt < 4; ++dt) {
        const bf16x8 vf = *reinterpret_cast<const bf16x8*>(
            &Vt[cur][swz(dt * 16 + (lane & 15), kk * 32 + (lane >> 4) * 8)]);
        acc_o[dt] = __builtin_amdgcn_mfma_f32_16x16x32_bf16(pf, vf, acc_o[dt], 0, 0, 0);
      }
    }
  };

  auto writeo = [&](int q0t, f32x4 (&acc_o)[4], float (&lr)[4]) {
#pragma unroll
    for (int dt = 0; dt < 4; ++dt)
#pragma unroll
      for (int r = 0; r < 4; ++r) {
        const int qg = q0t + wave * 16 + ((lane >> 4) << 2) + r;
        y[(size_t)(bT + qg) * 1024 + h * 64 + dt * 16 + (lane & 15)] =
            f2bf_bits(acc_o[dt][r] / lr[r]);
      }
  };

  bf16x8 qf_l[2], qf_h[2];
  loadq(lo * 64, qf_l);
  loadq(hi * 64, qf_h);
  f32x4 acc_l[4], acc_h[4];
#pragma unroll
  for (int dt = 0; dt < 4; ++dt) {
    f32x4 z = {0.f, 0.f, 0.f, 0.f};
    acc_l[dt] = z;
    acc_h[dt] = z;
  }
  float mr_l[4] = {-1e30f, -1e30f, -1e30f, -1e30f};
  float mr_h[4] = {-1e30f, -1e30f, -1e30f, -1e30f};
  float lr_l[4] = {0.f, 0.f, 0.f, 0.f};
  float lr_h[4] = {0.f, 0.f, 0.f, 0.f};

  stageK(0, 0);
  vload(0);
  vwrite(0);

  for (int jt = 0; jt <= hi; ++jt) {
    const int cur = jt & 1;
    __syncthreads();  // drains vmcnt/lgkm: buf[cur] ready; buf[cur^1] free
    if (jt < hi) {
      stageK((jt + 1) * 64, cur ^ 1);
      vload((jt + 1) * 64);
    }
    compute(qf_h, acc_h, mr_h, lr_h, hi * 64, jt * 64, jt == hi, cur);
    if (jt <= lo)
      compute(qf_l, acc_l, mr_l, lr_l, lo * 64, jt * 64, jt == lo, cur);
    if (jt < hi) vwrite(cur ^ 1);
  }

  writeo(hi * 64, acc_h, lr_h);
  writeo(lo * 64, acc_l, lr_l);
}

// ---------------- launch ----------------
extern "C" void kernel_launch(void* const* d_in, const int* in_sizes, int n_in,
                              void* d_out, int out_size, void* d_ws, size_t ws_size,
                              hipStream_t stream) {
  const float* x = (const float*)d_in[0];
  const float* kqv_w = (const float*)d_in[1];
  const float* kqv_b = (const float*)d_in[2];
  const float* proj_w = (const float*)d_in[3];
  const float* proj_b = (const float*)d_in[4];
  const float* ln1_g = (const float*)d_in[5];
  const float* ln1_b = (const float*)d_in[6];
  const float* ln2_g = (const float*)d_in[7];
  const float* ln2_b = (const float*)d_in[8];
  const float* fc1_w = (const float*)d_in[9];
  const float* fc1_b = (const float*)d_in[10];
  const float* fc2_w = (const float*)d_in[11];
  const float* fc2_b = (const float*)d_in[12];
  float* out = (float*)d_out;

  char* ws = (char*)d_ws;
  size_t off = 0;
  auto alloc = [&](size_t bytes) {
    char* p = ws + off;
    off += (bytes + 255) & ~(size_t)255;
    return p;
  };
  unsigned short* wk = (unsigned short*)alloc((size_t)3072 * 1024 * 2);
  unsigned short* wp = (unsigned short*)alloc((size_t)1024 * 1024 * 2);
  unsigned short* w1 = (unsigned short*)alloc((size_t)4096 * 1024 * 2);
  unsigned short* w2 = (unsigned short*)alloc((size_t)4096 * 1024 * 2);
  unsigned short* hbuf = (unsigned short*)alloc((size_t)8192 * 1024 * 2);
  unsigned short* kqvb = (unsigned short*)alloc((size_t)8192 * 3072 * 2);
  unsigned short* yb = (unsigned short*)alloc((size_t)8192 * 1024 * 2);
  float* x1 = (float*)alloc((size_t)8192 * 1024 * 4);
  unsigned short* a1 = (unsigned short*)alloc((size_t)8192 * 4096 * 2);

  // cast all weights to bf16 (single fused launch; 12582912 elems / 1024)
  cast4_kernel<<<dim3(12288), 256, 0, stream>>>(kqv_w, proj_w, fc1_w, fc2_w,
                                                wk, wp, w1, w2);

  // LN1 -> h (bf16)
  ln_kernel<<<dim3(8192), 256, 0, stream>>>(x, ln1_g, ln1_b, hbuf);

  // kqv = h @ kqv_w^T + b   [8192 x 3072]   grid (24,64)
  gemmS<0, 3072, 1024><<<dim3(3072 / 128, 8192 / 128), 256, 0, stream>>>(
      hbuf, wk, kqv_b, nullptr, kqvb, nullptr);

  // attention -> y (bf16)
  attn_kernel<<<dim3(128, 8), 256, 0, stream>>>(kqvb, yb);

  // x1 = x + y @ proj_w^T + b   (fp32)   grid (8,64)
  gemmS<1, 1024, 1024><<<dim3(1024 / 128, 8192 / 128), 256, 0, stream>>>(
      yb, wp, proj_b, x, nullptr, x1);

  // LN2 -> h (bf16, reuse)
  ln_kernel<<<dim3(8192), 256, 0, stream>>>(x1, ln2_g, ln2_b, hbuf);

  // a1 = gelu(h @ fc1_w^T + b)  [8192 x 4096]   grid (32,64)
  gemmS<2, 4096, 1024><<<dim3(4096 / 128, 8192 / 128), 256, 0, stream>>>(
      hbuf, w1, fc1_b, nullptr, a1, nullptr);

  // out = x1 + a1 @ fc2_w^T + b  (fp32)  grid (8,64), K=4096
  gemmS<1, 1024, 4096><<<dim3(1024 / 128, 8192 / 128), 256, 0, stream>>>(
      a1, w2, fc2_b, x1, nullptr, out);
}